// Round 12
// baseline (9116.801 us; speedup 1.0000x reference)
//
#include <hip/hip_runtime.h>

#define BATCH 512
#define SEQL  512
#define NIN   128
#define NH    512
#define NOUT  128
#define PRED  32
#define NSTEP (SEQL + PRED)

#define G_B 8
#define G_H 64
#define BT  64
#define UW  8               // hidden units per WG (B cols half-duplicated)
#define NWG (G_B * G_H)     // 512 WGs = 2 per CU, 2048 waves
#define NTHREADS 256

// LDS layout (shorts), weights in MFMA-FRAGMENT order (proven r7):
// frag f base = f*512 + lane*8 -> conflict-free ds_read_b128.
#define OFF_WIH  24576      // Whh: 3 gates x 16 ks = 48 frags
#define OFF_WOUT 30720      // Wih: 3 gates x 4 ks = 12 frags
#define OFF_TR   38912      // Wout: 16 ks frags
#define LDS_SH   39680      // + 4 waves x 16 rows x 12 shorts transpose pad

typedef short bf16x8 __attribute__((ext_vector_type(8)));
typedef float f32x4 __attribute__((ext_vector_type(4)));
typedef unsigned int u32x4 __attribute__((ext_vector_type(4)));

#define MFMA __builtin_amdgcn_mfma_f32_16x16x32_bf16

__device__ __forceinline__ unsigned short f2bf(float f) {
    unsigned int u = __float_as_uint(f);
    u = (u + 0x7fffu + ((u >> 16) & 1u)) >> 16;   // RTNE
    return (unsigned short)u;
}
__device__ __forceinline__ float sigm(float x) {
    x = fminf(fmaxf(x, -30.f), 30.f);
    return 1.f / (1.f + __expf(-x));
}
__device__ __forceinline__ float tanh_f(float x) {
    x = fminf(fmaxf(x, -15.f), 15.f);
    float e = __expf(2.f * x);
    return (e - 1.f) / (e + 1.f);
}

// Zero h0 (hbuf buffer 0) and the flag rows with sc1 stores (land at the
// chip-coherent MALL point where the main kernel's sc1 loads read).
__global__ __launch_bounds__(256) void zero_kernel(unsigned short* hbuf, int* cnt)
{
    const int tid = threadIdx.x, wg = blockIdx.x;
    u32x4 z = {0, 0, 0, 0};
    char* base = (char*)hbuf + ((wg * 256 + tid) * 32);   // 64*256*32B = 512 KiB
    asm volatile("global_store_dwordx4 %0, %1, off sc1" :: "v"(base), "v"(z) : "memory");
    asm volatile("global_store_dwordx4 %0, %1, off offset:16 sc1" :: "v"(base), "v"(z) : "memory");
    if (wg == 0) {
        char* p = (char*)cnt + tid * 16;   // 4 KiB: 8 groups x 128 ints
        asm volatile("global_store_dwordx4 %0, %1, off sc1" :: "v"(p), "v"(z) : "memory");
    }
}

// Persistent GRU kernel. WG (bg, hs): batch rows [bg*64,+64), units [hs*8,+8).
// Round-7 sc1/MALL protocol (PROVEN correct; rounds 9-11's local-L2 variants
// all failed) at 2x the thread-level parallelism: 512 WGs / 2048 waves
// (2 WGs/CU, 8 waves/CU) to hide the MALL round-trip latency.
// MFMA B-operands carry each unit twice (cols 0-7 == 8-15); duplicate lanes
// compute bit-identical h (same C, same biases) — benign.
__global__ __launch_bounds__(NTHREADS, 1) void gru_kernel(
    const float* __restrict__ z_seq, const float* __restrict__ W_ih,
    const float* __restrict__ W_hh, const float* __restrict__ b_ih,
    const float* __restrict__ b_hh, const float* __restrict__ W_out,
    const float* __restrict__ b_out, float* __restrict__ out,
    unsigned short* __restrict__ hbuf, int* __restrict__ cnt)
{
    __shared__ unsigned short s_w[LDS_SH];
    const int tid = threadIdx.x;
    const int wg  = blockIdx.x;
    const int bg  = wg & 7;
    const int hs  = wg >> 3;          // 0..63

    // ---- stage weights in fragment-linear order (fp32 -> bf16) ----
    for (int i = tid; i < 24576; i += NTHREADS) {
        int e = i & 7, ln = (i >> 3) & 63, ks = (i >> 9) & 15, g = i >> 13;
        int unit = hs * UW + (ln & 7);             // cols duplicated x2
        int k = ks * 32 + (ln >> 4) * 8 + e;
        s_w[i] = f2bf(W_hh[(g * 512 + unit) * 512 + k]);
    }
    for (int i = tid; i < 6144; i += NTHREADS) {
        int e = i & 7, ln = (i >> 3) & 63, ks = (i >> 9) & 3, g = i >> 11;
        int unit = hs * UW + (ln & 7);
        int k = ks * 32 + (ln >> 4) * 8 + e;
        s_w[OFF_WIH + i] = f2bf(W_ih[(g * 512 + unit) * 128 + k]);
    }
    for (int i = tid; i < 8192; i += NTHREADS) {
        int e = i & 7, ln = (i >> 3) & 63, ks = i >> 9;
        int ocol = hs * 2 + (ln & 1);              // cols duplicated x8
        int k = ks * 32 + (ln >> 4) * 8 + e;
        s_w[OFF_WOUT + i] = f2bf(W_out[ocol * 512 + k]);
    }
    __syncthreads();

    const int lane = tid & 63;
    const int wave = tid >> 6;
    const int li   = lane & 15;       // MFMA row-of-A / col-of-B / col-of-C
    const int kq   = lane >> 4;       // k-chunk selector
    const int jg   = hs * UW + (li & 7);   // this lane's hidden unit

    const float bihr = b_ih[jg], bihz = b_ih[NH + jg], bihn = b_ih[2 * NH + jg];
    const float bhhr = b_hh[jg], bhhz = b_hh[NH + jg], bhhn = b_hh[2 * NH + jg];
    const float bo   = b_out[hs * 2 + (li & 1)];

    const int aRow = bg * BT + wave * 16 + li;        // batch row for A frags
    const int cRow = bg * BT + wave * 16 + kq * 4;    // C rows (+q)
    float hreg[4] = {0.f, 0.f, 0.f, 0.f};             // fp32 h state in regs

    const unsigned short* fb = s_w + lane * 8;            // per-lane frag base
    unsigned short* tr = s_w + OFF_TR + wave * 192;       // 16 rows x 12 shorts

    int* gflags = cnt + bg * 128;         // 64 flag ints per group (512B apart)
    int* myFlag = gflags + hs;
    int  dead   = 0;

    // ---- prologue: input-side pre-activations for t = 0 ----
    f32x4 ir = {0,0,0,0}, iz = {0,0,0,0}, in = {0,0,0,0};
    {
        const float* zrow = z_seq + ((long)aRow * SEQL + 0) * NIN + kq * 8;
#pragma unroll
        for (int ks = 0; ks < 4; ++ks) {
            float4 z0 = *(const float4*)(zrow + ks * 32);
            float4 z1 = *(const float4*)(zrow + ks * 32 + 4);
            union { bf16x8 v; unsigned short u[8]; } az;
            az.u[0] = f2bf(z0.x); az.u[1] = f2bf(z0.y);
            az.u[2] = f2bf(z0.z); az.u[3] = f2bf(z0.w);
            az.u[4] = f2bf(z1.x); az.u[5] = f2bf(z1.y);
            az.u[6] = f2bf(z1.z); az.u[7] = f2bf(z1.w);
            ir = MFMA(az.v, *(const bf16x8*)(fb + OFF_WIH + ks * 512), ir, 0, 0, 0);
            iz = MFMA(az.v, *(const bf16x8*)(fb + OFF_WIH + 2048 + ks * 512), iz, 0, 0, 0);
            in = MFMA(az.v, *(const bf16x8*)(fb + OFF_WIH + 4096 + ks * 512), in, 0, 0, 0);
        }
    }

    for (int t = 0; t <= NSTEP; ++t) {
        const unsigned short* hin  = hbuf + (t & 1) * (BATCH * NH);
        unsigned short*       hout = hbuf + ((t & 1) ^ 1) * (BATCH * NH);

        // A fragments: sc1 = agent-scope load from the MALL coherence point
        const unsigned short* hrow = hin + aRow * NH + kq * 8;
        bf16x8 a[16];
#pragma unroll
        for (int ks = 0; ks < 16; ++ks)
            asm volatile("global_load_dwordx4 %0, %1, off offset:%2 sc1"
                         : "=v"(a[ks]) : "v"(hrow), "i"(ks * 64) : "memory");
        asm volatile("s_waitcnt vmcnt(0)" ::: "memory");
        __builtin_amdgcn_sched_barrier(0);

        // decode: a[] holds h_t; y_td needs h_{SEQL+1+td} -> emit at t=SEQL+1+td
        if (t > SEQL) {
            int td = t - SEQL - 1;
            f32x4 y4 = {0, 0, 0, 0};
#pragma unroll
            for (int ks = 0; ks < 16; ++ks)
                y4 = MFMA(a[ks], *(const bf16x8*)(fb + OFF_WOUT + ks * 512), y4, 0, 0, 0);
            if (li < 2) {
#pragma unroll
                for (int q = 0; q < 4; ++q)
                    out[((long)(cRow + q) * PRED + td) * NOUT + hs * 2 + li] = y4[q] + bo;
            }
        }
        if (t == NSTEP) break;

        // hidden-side MFMA: fragment-linear B reads (conflict-free)
        f32x4 hr = {0,0,0,0}, hz = {0,0,0,0}, hn = {0,0,0,0};
#pragma unroll
        for (int ks = 0; ks < 16; ++ks) {
            hr = MFMA(a[ks], *(const bf16x8*)(fb + ks * 512), hr, 0, 0, 0);
            hz = MFMA(a[ks], *(const bf16x8*)(fb + 8192 + ks * 512), hz, 0, 0, 0);
            hn = MFMA(a[ks], *(const bf16x8*)(fb + 16384 + ks * 512), hn, 0, 0, 0);
        }

        // gate math -> bf16 into per-wave LDS transpose tile (stride 12).
        // Lanes li and li+8 write the same address with bit-identical values.
#pragma unroll
        for (int q = 0; q < 4; ++q) {
            float r  = sigm(bihr + ir[q] + bhhr + hr[q]);
            float zz = sigm(bihz + iz[q] + bhhz + hz[q]);
            float nn = tanh_f(bihn + in[q] + r * (bhhn + hn[q]));
            float hq = (1.f - zz) * nn + zz * hreg[q];
            hreg[q]  = hq;
            tr[(kq * 4 + q) * 12 + (li & 7)] = f2bf(hq);
        }
        asm volatile("s_waitcnt lgkmcnt(0)" ::: "memory");
        __builtin_amdgcn_sched_barrier(0);

        // coalesced h store: 16 lanes x dwordx4 sc1 (16 rows x 16B)
        if (lane < 16) {
            bf16x8 hv = *(const bf16x8*)(tr + lane * 12);
            int grow = bg * BT + wave * 16 + lane;
            unsigned short* hp = hout + grow * NH + hs * UW;
            asm volatile("global_store_dwordx4 %0, %1, off sc1"
                         :: "v"(hp), "v"(hv) : "memory");
        }
        asm volatile("s_waitcnt vmcnt(0)" ::: "memory");
        __syncthreads();
        if (tid == 0) {
            int v = t + 1;
            asm volatile("global_store_dword %0, %1, off sc1"
                         :: "v"(myFlag), "v"(v) : "memory");
        }

        // ---- barrier shadow: input-side pre-activations for t+1 ----
        f32x4 nir = {0,0,0,0}, niz = {0,0,0,0}, nin = {0,0,0,0};
        if (t + 1 < SEQL) {
            const float* zrow = z_seq + ((long)aRow * SEQL + (t + 1)) * NIN + kq * 8;
#pragma unroll
            for (int ks = 0; ks < 4; ++ks) {
                float4 z0 = *(const float4*)(zrow + ks * 32);
                float4 z1 = *(const float4*)(zrow + ks * 32 + 4);
                union { bf16x8 v; unsigned short u[8]; } az;
                az.u[0] = f2bf(z0.x); az.u[1] = f2bf(z0.y);
                az.u[2] = f2bf(z0.z); az.u[3] = f2bf(z0.w);
                az.u[4] = f2bf(z1.x); az.u[5] = f2bf(z1.y);
                az.u[6] = f2bf(z1.z); az.u[7] = f2bf(z1.w);
                nir = MFMA(az.v, *(const bf16x8*)(fb + OFF_WIH + ks * 512), nir, 0, 0, 0);
                niz = MFMA(az.v, *(const bf16x8*)(fb + OFF_WIH + 2048 + ks * 512), niz, 0, 0, 0);
                nin = MFMA(az.v, *(const bf16x8*)(fb + OFF_WIH + 4096 + ks * 512), nin, 0, 0, 0);
            }
        }

        // ---- flag poll: min over the group's 64 flags >= t+1 ----
        // Plain sc1 loads (no RMW); "=&v" early-clobber mandatory (round 6).
        const int target = t + 1;
        int bail = 0;
        if (!dead && lane == 0) {
            int patience = 4000000;
            for (;;) {
                int4 f0, f1, f2, f3, f4, f5, f6, f7;
                int4 g0, g1, g2, g3, g4, g5, g6, g7;
                asm volatile(
                    "global_load_dwordx4 %0, %16, off sc1\n\t"
                    "global_load_dwordx4 %1, %16, off offset:16 sc1\n\t"
                    "global_load_dwordx4 %2, %16, off offset:32 sc1\n\t"
                    "global_load_dwordx4 %3, %16, off offset:48 sc1\n\t"
                    "global_load_dwordx4 %4, %16, off offset:64 sc1\n\t"
                    "global_load_dwordx4 %5, %16, off offset:80 sc1\n\t"
                    "global_load_dwordx4 %6, %16, off offset:96 sc1\n\t"
                    "global_load_dwordx4 %7, %16, off offset:112 sc1\n\t"
                    "global_load_dwordx4 %8, %16, off offset:128 sc1\n\t"
                    "global_load_dwordx4 %9, %16, off offset:144 sc1\n\t"
                    "global_load_dwordx4 %10, %16, off offset:160 sc1\n\t"
                    "global_load_dwordx4 %11, %16, off offset:176 sc1\n\t"
                    "global_load_dwordx4 %12, %16, off offset:192 sc1\n\t"
                    "global_load_dwordx4 %13, %16, off offset:208 sc1\n\t"
                    "global_load_dwordx4 %14, %16, off offset:224 sc1\n\t"
                    "global_load_dwordx4 %15, %16, off offset:240 sc1\n\t"
                    "s_waitcnt vmcnt(0)"
                    : "=&v"(f0), "=&v"(f1), "=&v"(f2), "=&v"(f3),
                      "=&v"(f4), "=&v"(f5), "=&v"(f6), "=&v"(f7),
                      "=&v"(g0), "=&v"(g1), "=&v"(g2), "=&v"(g3),
                      "=&v"(g4), "=&v"(g5), "=&v"(g6), "=&v"(g7)
                    : "v"(gflags) : "memory");
                int m0 = min(min(min(f0.x, f0.y), min(f0.z, f0.w)),
                             min(min(f1.x, f1.y), min(f1.z, f1.w)));
                int m1 = min(min(min(f2.x, f2.y), min(f2.z, f2.w)),
                             min(min(f3.x, f3.y), min(f3.z, f3.w)));
                int m2 = min(min(min(f4.x, f4.y), min(f4.z, f4.w)),
                             min(min(f5.x, f5.y), min(f5.z, f5.w)));
                int m3 = min(min(min(f6.x, f6.y), min(f6.z, f6.w)),
                             min(min(f7.x, f7.y), min(f7.z, f7.w)));
                int m4 = min(min(min(g0.x, g0.y), min(g0.z, g0.w)),
                             min(min(g1.x, g1.y), min(g1.z, g1.w)));
                int m5 = min(min(min(g2.x, g2.y), min(g2.z, g2.w)),
                             min(min(g3.x, g3.y), min(g3.z, g3.w)));
                int m6 = min(min(min(g4.x, g4.y), min(g4.z, g4.w)),
                             min(min(g5.x, g5.y), min(g5.z, g5.w)));
                int m7 = min(min(min(g6.x, g6.y), min(g6.z, g6.w)),
                             min(min(g7.x, g7.y), min(g7.z, g7.w)));
                int m = min(min(min(m0, m1), min(m2, m3)),
                            min(min(m4, m5), min(m6, m7)));
                if (m >= target) break;
                if (--patience == 0) { bail = 1; break; }
            }
        }
        dead |= __builtin_amdgcn_readfirstlane(bail);
        __builtin_amdgcn_sched_barrier(0);

        ir = nir; iz = niz; in = nin;
    }
}

extern "C" void kernel_launch(void* const* d_in, const int* in_sizes, int n_in,
                              void* d_out, int out_size, void* d_ws, size_t ws_size,
                              hipStream_t stream)
{
    const float* z_seq = (const float*)d_in[0];
    const float* W_ih  = (const float*)d_in[1];
    const float* W_hh  = (const float*)d_in[2];
    const float* b_ih  = (const float*)d_in[3];
    const float* b_hh  = (const float*)d_in[4];
    const float* W_out = (const float*)d_in[5];
    const float* b_out = (const float*)d_in[6];
    float* out = (float*)d_out;

    unsigned short* hbuf = (unsigned short*)d_ws;                   // 2 x [512][512] bf16
    int* cnt = (int*)((char*)d_ws + (size_t)2 * BATCH * NH * 2);    // 8 x 128 flag ints

    zero_kernel<<<dim3(64), dim3(256), 0, stream>>>(hbuf, cnt);
    gru_kernel<<<dim3(NWG), dim3(NTHREADS), 0, stream>>>(
        z_seq, W_ih, W_hh, b_ih, b_hh, W_out, b_out, out, hbuf, cnt);
}

// Round 13
// 4065.126 us; speedup vs baseline: 2.2427x; 2.2427x over previous
//
#include <hip/hip_runtime.h>

#define BATCH 512
#define SEQL  512
#define NIN   128
#define NH    512
#define NOUT  128
#define PRED  32
#define NSTEP (SEQL + PRED)

#define G_B 16              // 16 batch groups x 32 rows
#define G_H 32              // 32 unit slices x 16 units
#define BT  32              // batch rows per group
#define NWG (G_B * G_H)     // 512 WGs x 128 thr = 2 WGs/CU, decoupled domains
#define NTHREADS 128

// LDS layout (shorts), weights in MFMA-FRAGMENT order (round 7, proven:
// conflict-free ds_read_b128): frag f base = f*512 + lane*8.
#define OFF_WIH  24576
#define OFF_WOUT 30720
#define OFF_TR   38912
#define LDS_SH   39680      // + 2 waves * 384 transpose scratch = 79360 B

typedef short bf16x8 __attribute__((ext_vector_type(8)));
typedef float f32x4 __attribute__((ext_vector_type(4)));
typedef unsigned int u32x4 __attribute__((ext_vector_type(4)));

#define MFMA __builtin_amdgcn_mfma_f32_16x16x32_bf16

__device__ __forceinline__ unsigned short f2bf(float f) {
    unsigned int u = __float_as_uint(f);
    u = (u + 0x7fffu + ((u >> 16) & 1u)) >> 16;   // RTNE
    return (unsigned short)u;
}
__device__ __forceinline__ float sigm(float x) {
    x = fminf(fmaxf(x, -30.f), 30.f);
    return 1.f / (1.f + __expf(-x));
}
__device__ __forceinline__ float tanh_f(float x) {
    x = fminf(fmaxf(x, -15.f), 15.f);
    float e = __expf(2.f * x);
    return (e - 1.f) / (e + 1.f);
}

// Zero h0 (hbuf buffer 0) and the 16 flag rows (4 KiB) with sc1 stores (land
// at the chip-coherent MALL point where the main kernel's sc1 loads read).
__global__ __launch_bounds__(256) void zero_kernel(unsigned short* hbuf, int* cnt)
{
    const int tid = threadIdx.x, wg = blockIdx.x;
    u32x4 z = {0, 0, 0, 0};
    char* base = (char*)hbuf + ((wg * 256 + tid) * 32);   // 64*256*32B = 512 KiB
    asm volatile("global_store_dwordx4 %0, %1, off sc1" :: "v"(base), "v"(z) : "memory");
    asm volatile("global_store_dwordx4 %0, %1, off offset:16 sc1" :: "v"(base), "v"(z) : "memory");
    if (wg == 0) {
        char* p = (char*)cnt + tid * 16;   // 4 KiB: 16 groups x 64 ints
        asm volatile("global_store_dwordx4 %0, %1, off sc1" :: "v"(p), "v"(z) : "memory");
    }
}

// Persistent GRU kernel. WG (bg, hs): batch rows [bg*32,+32), units [hs*16,+16).
// Round-7 sc1/MALL protocol (the only correct one measured) with DECOUPLED
// SYNC DOMAINS: 512 WGs of 2 waves, 2 WGs/CU from different batch groups —
// when one WG stalls in its poll, the co-resident WG computes. Aggregate h
// traffic unchanged (BATCH*NH*2B*G_H = 16 MB/step).
__global__ __launch_bounds__(NTHREADS, 1) void gru_kernel(
    const float* __restrict__ z_seq, const float* __restrict__ W_ih,
    const float* __restrict__ W_hh, const float* __restrict__ b_ih,
    const float* __restrict__ b_hh, const float* __restrict__ W_out,
    const float* __restrict__ b_out, float* __restrict__ out,
    unsigned short* __restrict__ hbuf, int* __restrict__ cnt)
{
    __shared__ unsigned short s_w[LDS_SH];
    const int tid = threadIdx.x;
    const int wg  = blockIdx.x;
    const int bg  = wg & 15;          // 16 batch groups
    const int hs  = wg >> 4;          // 32 unit slices

    // ---- stage weights in fragment-linear order (fp32 -> bf16) ----
    for (int i = tid; i < 24576; i += NTHREADS) {
        int e = i & 7, ln = (i >> 3) & 63, ks = (i >> 9) & 15, g = i >> 13;
        int unit = hs * 16 + (ln & 15);
        int k = ks * 32 + (ln >> 4) * 8 + e;
        s_w[i] = f2bf(W_hh[(g * 512 + unit) * 512 + k]);
    }
    for (int i = tid; i < 6144; i += NTHREADS) {
        int e = i & 7, ln = (i >> 3) & 63, ks = (i >> 9) & 3, g = i >> 11;
        int unit = hs * 16 + (ln & 15);
        int k = ks * 32 + (ln >> 4) * 8 + e;
        s_w[OFF_WIH + i] = f2bf(W_ih[(g * 512 + unit) * 128 + k]);
    }
    for (int i = tid; i < 8192; i += NTHREADS) {
        int e = i & 7, ln = (i >> 3) & 63, ks = i >> 9;
        int ocol = hs * 4 + (ln & 3);           // cols duplicated x4
        int k = ks * 32 + (ln >> 4) * 8 + e;
        s_w[OFF_WOUT + i] = f2bf(W_out[ocol * 512 + k]);
    }
    __syncthreads();

    const int lane = tid & 63;
    const int wave = tid >> 6;        // 0..1
    const int li   = lane & 15;       // MFMA row-of-A / col-of-B / col-of-C
    const int kq   = lane >> 4;       // k-chunk selector
    const int jg   = hs * 16 + li;    // global hidden unit of this lane

    const float bihr = b_ih[jg], bihz = b_ih[NH + jg], bihn = b_ih[2 * NH + jg];
    const float bhhr = b_hh[jg], bhhz = b_hh[NH + jg], bhhn = b_hh[2 * NH + jg];
    const float bo   = b_out[hs * 4 + (li & 3)];

    const int aRow = bg * BT + wave * 16 + li;        // batch row for A frags
    const int cRow = bg * BT + wave * 16 + kq * 4;    // C rows (+q)
    float hreg[4] = {0.f, 0.f, 0.f, 0.f};             // fp32 h state in regs

    const unsigned short* fb = s_w + lane * 8;            // per-lane frag base
    unsigned short* tr = s_w + OFF_TR + wave * 384;       // transpose scratch

    int* gflags = cnt + bg * 64;          // 32 flag ints per group (256B apart)
    int* myFlag = gflags + hs;
    int  dead   = 0;

    // ---- prologue: input-side pre-activations for t = 0 ----
    f32x4 ir = {0,0,0,0}, iz = {0,0,0,0}, in = {0,0,0,0};
    {
        const float* zrow = z_seq + ((long)aRow * SEQL + 0) * NIN + kq * 8;
#pragma unroll
        for (int ks = 0; ks < 4; ++ks) {
            float4 z0 = *(const float4*)(zrow + ks * 32);
            float4 z1 = *(const float4*)(zrow + ks * 32 + 4);
            union { bf16x8 v; unsigned short u[8]; } az;
            az.u[0] = f2bf(z0.x); az.u[1] = f2bf(z0.y);
            az.u[2] = f2bf(z0.z); az.u[3] = f2bf(z0.w);
            az.u[4] = f2bf(z1.x); az.u[5] = f2bf(z1.y);
            az.u[6] = f2bf(z1.z); az.u[7] = f2bf(z1.w);
            ir = MFMA(az.v, *(const bf16x8*)(fb + OFF_WIH + ks * 512), ir, 0, 0, 0);
            iz = MFMA(az.v, *(const bf16x8*)(fb + OFF_WIH + 2048 + ks * 512), iz, 0, 0, 0);
            in = MFMA(az.v, *(const bf16x8*)(fb + OFF_WIH + 4096 + ks * 512), in, 0, 0, 0);
        }
    }

    for (int t = 0; t <= NSTEP; ++t) {
        const unsigned short* hin  = hbuf + (t & 1) * (BATCH * NH);
        unsigned short*       hout = hbuf + ((t & 1) ^ 1) * (BATCH * NH);

        // A fragments: sc1 = agent-scope load from the MALL coherence point
        const unsigned short* hrow = hin + aRow * NH + kq * 8;
        bf16x8 a[16];
#pragma unroll
        for (int ks = 0; ks < 16; ++ks)
            asm volatile("global_load_dwordx4 %0, %1, off offset:%2 sc1"
                         : "=v"(a[ks]) : "v"(hrow), "i"(ks * 64) : "memory");
        asm volatile("s_waitcnt vmcnt(0)" ::: "memory");
        __builtin_amdgcn_sched_barrier(0);

        // decode: a[] holds h_t; y_td needs h_{SEQL+1+td} -> emit at t=SEQL+1+td
        if (t > SEQL) {
            int td = t - SEQL - 1;
            f32x4 y4 = {0, 0, 0, 0};
#pragma unroll
            for (int ks = 0; ks < 16; ++ks)
                y4 = MFMA(a[ks], *(const bf16x8*)(fb + OFF_WOUT + ks * 512), y4, 0, 0, 0);
            if (li < 4) {
#pragma unroll
                for (int q = 0; q < 4; ++q)
                    out[((long)(cRow + q) * PRED + td) * NOUT + hs * 4 + li] = y4[q] + bo;
            }
        }
        if (t == NSTEP) break;

        // hidden-side MFMA: fragment-linear B reads (zero bank conflicts)
        f32x4 hr = {0,0,0,0}, hz = {0,0,0,0}, hn = {0,0,0,0};
#pragma unroll
        for (int ks = 0; ks < 16; ++ks) {
            hr = MFMA(a[ks], *(const bf16x8*)(fb + ks * 512), hr, 0, 0, 0);
            hz = MFMA(a[ks], *(const bf16x8*)(fb + 8192 + ks * 512), hz, 0, 0, 0);
            hn = MFMA(a[ks], *(const bf16x8*)(fb + 16384 + ks * 512), hn, 0, 0, 0);
        }

        // gate math -> bf16 into per-wave LDS transpose tile (rows stride 24)
#pragma unroll
        for (int q = 0; q < 4; ++q) {
            float r  = sigm(bihr + ir[q] + bhhr + hr[q]);
            float zz = sigm(bihz + iz[q] + bhhz + hz[q]);
            float nn = tanh_f(bihn + in[q] + r * (bhhn + hn[q]));
            float hq = (1.f - zz) * nn + zz * hreg[q];
            hreg[q]  = hq;
            tr[(kq * 4 + q) * 24 + li] = f2bf(hq);
        }
        asm volatile("s_waitcnt lgkmcnt(0)" ::: "memory");
        __builtin_amdgcn_sched_barrier(0);

        // coalesced h store: 32 lanes x dwordx4 sc1 (16 rows x 2 chunks)
        if (lane < 32) {
            bf16x8 hv = *(const bf16x8*)(tr + (lane >> 1) * 24 + (lane & 1) * 8);
            int grow = bg * BT + wave * 16 + (lane >> 1);
            unsigned short* hp = hout + grow * NH + hs * 16 + (lane & 1) * 8;
            asm volatile("global_store_dwordx4 %0, %1, off sc1"
                         :: "v"(hp), "v"(hv) : "memory");
        }
        asm volatile("s_waitcnt vmcnt(0)" ::: "memory");
        __syncthreads();
        if (tid == 0) {
            int v = t + 1;
            asm volatile("global_store_dword %0, %1, off sc1"
                         :: "v"(myFlag), "v"(v) : "memory");
        }

        // ---- barrier shadow: input-side pre-activations for t+1 ----
        f32x4 nir = {0,0,0,0}, niz = {0,0,0,0}, nin = {0,0,0,0};
        if (t + 1 < SEQL) {
            const float* zrow = z_seq + ((long)aRow * SEQL + (t + 1)) * NIN + kq * 8;
#pragma unroll
            for (int ks = 0; ks < 4; ++ks) {
                float4 z0 = *(const float4*)(zrow + ks * 32);
                float4 z1 = *(const float4*)(zrow + ks * 32 + 4);
                union { bf16x8 v; unsigned short u[8]; } az;
                az.u[0] = f2bf(z0.x); az.u[1] = f2bf(z0.y);
                az.u[2] = f2bf(z0.z); az.u[3] = f2bf(z0.w);
                az.u[4] = f2bf(z1.x); az.u[5] = f2bf(z1.y);
                az.u[6] = f2bf(z1.z); az.u[7] = f2bf(z1.w);
                nir = MFMA(az.v, *(const bf16x8*)(fb + OFF_WIH + ks * 512), nir, 0, 0, 0);
                niz = MFMA(az.v, *(const bf16x8*)(fb + OFF_WIH + 2048 + ks * 512), niz, 0, 0, 0);
                nin = MFMA(az.v, *(const bf16x8*)(fb + OFF_WIH + 4096 + ks * 512), nin, 0, 0, 0);
            }
        }

        // ---- flag-vector poll: plain sc1 loads of the 32 group flags ----
        // "=&v" early-clobber mandatory (round-6 crash lesson).
        const int target = t + 1;
        int bail = 0;
        if (!dead && lane == 0) {
            int patience = 2000000;
            for (;;) {
                int4 f0, f1, f2, f3, f4, f5, f6, f7;
                asm volatile(
                    "global_load_dwordx4 %0, %8, off sc1\n\t"
                    "global_load_dwordx4 %1, %8, off offset:16 sc1\n\t"
                    "global_load_dwordx4 %2, %8, off offset:32 sc1\n\t"
                    "global_load_dwordx4 %3, %8, off offset:48 sc1\n\t"
                    "global_load_dwordx4 %4, %8, off offset:64 sc1\n\t"
                    "global_load_dwordx4 %5, %8, off offset:80 sc1\n\t"
                    "global_load_dwordx4 %6, %8, off offset:96 sc1\n\t"
                    "global_load_dwordx4 %7, %8, off offset:112 sc1\n\t"
                    "s_waitcnt vmcnt(0)"
                    : "=&v"(f0), "=&v"(f1), "=&v"(f2), "=&v"(f3),
                      "=&v"(f4), "=&v"(f5), "=&v"(f6), "=&v"(f7)
                    : "v"(gflags) : "memory");
                int m0 = min(min(min(f0.x, f0.y), min(f0.z, f0.w)),
                             min(min(f1.x, f1.y), min(f1.z, f1.w)));
                int m1 = min(min(min(f2.x, f2.y), min(f2.z, f2.w)),
                             min(min(f3.x, f3.y), min(f3.z, f3.w)));
                int m2 = min(min(min(f4.x, f4.y), min(f4.z, f4.w)),
                             min(min(f5.x, f5.y), min(f5.z, f5.w)));
                int m3 = min(min(min(f6.x, f6.y), min(f6.z, f6.w)),
                             min(min(f7.x, f7.y), min(f7.z, f7.w)));
                if (min(min(m0, m1), min(m2, m3)) >= target) break;
                if (--patience == 0) { bail = 1; break; }
            }
        }
        dead |= __builtin_amdgcn_readfirstlane(bail);
        __builtin_amdgcn_sched_barrier(0);

        ir = nir; iz = niz; in = nin;
    }
}

extern "C" void kernel_launch(void* const* d_in, const int* in_sizes, int n_in,
                              void* d_out, int out_size, void* d_ws, size_t ws_size,
                              hipStream_t stream)
{
    const float* z_seq = (const float*)d_in[0];
    const float* W_ih  = (const float*)d_in[1];
    const float* W_hh  = (const float*)d_in[2];
    const float* b_ih  = (const float*)d_in[3];
    const float* b_hh  = (const float*)d_in[4];
    const float* W_out = (const float*)d_in[5];
    const float* b_out = (const float*)d_in[6];
    float* out = (float*)d_out;

    unsigned short* hbuf = (unsigned short*)d_ws;                   // 2 x [512][512] bf16
    int* cnt = (int*)((char*)d_ws + (size_t)2 * BATCH * NH * 2);    // 16 x 64 flag ints

    zero_kernel<<<dim3(64), dim3(256), 0, stream>>>(hbuf, cnt);
    gru_kernel<<<dim3(NWG), dim3(NTHREADS), 0, stream>>>(
        z_seq, W_ih, W_hh, b_ih, b_hh, W_out, b_out, out, hbuf, cnt);
}

// Round 14
// 2769.840 us; speedup vs baseline: 3.2915x; 1.4676x over previous
//
#include <hip/hip_runtime.h>

#define BATCH 512
#define SEQL  512
#define NIN   128
#define NH    512
#define NOUT  128
#define PRED  32
#define NSTEP (SEQL + PRED)

#define G_B 8
#define G_H 32
#define BT  64
#define NWG (G_B * G_H)
#define NTHREADS 256

// LDS layout (shorts), weights in MFMA-FRAGMENT order (round 7, proven):
// frag f base = f*512 + lane*8 -> conflict-free ds_read_b128.
#define OFF_WIH  24576
#define OFF_WOUT 30720
#define OFF_TR   38912
#define LDS_SH   40448

// Workspace byte map:
//  [0, 1MB)        hbuf (2 x 512x512 bf16) — written ONLY by sc1 group stores
//                  (never zeroed: t=0 uses a[]=0, buffer 0 is never read)
//  SLOW_FLAG_OFF   8 groups x 64 ints — zeroed (sc1), sc1-polled (slow path)
//  XCD_OFF         8 x 32 ints — zeroed, XCD-consistency exchange
//  CANT_OFF        8 x 32 ints — zeroed, canary test words
//  CANC_OFF        8 x 32 ints — zeroed, canary sequencing flags
//  FAST_FLAG_OFF   8 x 64 ints — NOT zeroed by zero_kernel; owner-initialized
//                  (only ever written by same-group sc1 stores -> no foreign-
//                  XCD writes -> plain-read-after-inv is canary-covered)
#define SLOW_FLAG_OFF 1048576
#define XCD_OFF       1052672
#define CANT_OFF      1053696
#define CANC_OFF      1054720
#define FAST_FLAG_OFF 1056768
#define WS_NEED       1058816

typedef short bf16x8 __attribute__((ext_vector_type(8)));
typedef float f32x4 __attribute__((ext_vector_type(4)));
typedef unsigned int u32x4 __attribute__((ext_vector_type(4)));

#define MFMA __builtin_amdgcn_mfma_f32_16x16x32_bf16

template<bool B> struct BC { static constexpr bool value = B; };

__device__ __forceinline__ unsigned short f2bf(float f) {
    unsigned int u = __float_as_uint(f);
    u = (u + 0x7fffu + ((u >> 16) & 1u)) >> 16;   // RTNE
    return (unsigned short)u;
}
__device__ __forceinline__ float sigm(float x) {
    x = fminf(fmaxf(x, -30.f), 30.f);
    return 1.f / (1.f + __expf(-x));
}
__device__ __forceinline__ float tanh_f(float x) {
    x = fminf(fmaxf(x, -15.f), 15.f);
    float e = __expf(2.f * x);
    return (e - 1.f) / (e + 1.f);
}
__device__ __forceinline__ int poll_word_sc1(const int* p) {
    int v;
    asm volatile("global_load_dword %0, %1, off sc1\n\ts_waitcnt vmcnt(0)"
                 : "=v"(v) : "v"(p) : "memory");
    return v;
}

// Read a 32-int flag row (128B), return (min, max). "=&v" early-clobber
// mandatory (round-6 crash lesson).
// sc1 variant: reads the chip-coherent MALL point (always fresh, slow path).
// inv variant: buffer_inv (L1 invalidate) + PLAIN loads -> local-XCD L2.
//   Safe ONLY when every store to these lines is a same-XCD sc1 store whose
//   L2 pass-through updates/invalidates the line — verified at runtime by
//   the canary probe; otherwise the group uses the sc1 path.
#define POLL_ROW_BODY(PREFIX, SCBITS)                                      \
    int4 f0, f1, f2, f3, f4, f5, f6, f7;                                   \
    asm volatile(                                                          \
        PREFIX                                                             \
        "global_load_dwordx4 %0, %8, off " SCBITS "\n\t"                   \
        "global_load_dwordx4 %1, %8, off offset:16 " SCBITS "\n\t"         \
        "global_load_dwordx4 %2, %8, off offset:32 " SCBITS "\n\t"         \
        "global_load_dwordx4 %3, %8, off offset:48 " SCBITS "\n\t"         \
        "global_load_dwordx4 %4, %8, off offset:64 " SCBITS "\n\t"         \
        "global_load_dwordx4 %5, %8, off offset:80 " SCBITS "\n\t"         \
        "global_load_dwordx4 %6, %8, off offset:96 " SCBITS "\n\t"         \
        "global_load_dwordx4 %7, %8, off offset:112 " SCBITS "\n\t"        \
        "s_waitcnt vmcnt(0)"                                               \
        : "=&v"(f0), "=&v"(f1), "=&v"(f2), "=&v"(f3),                      \
          "=&v"(f4), "=&v"(f5), "=&v"(f6), "=&v"(f7)                       \
        : "v"(p) : "memory");                                              \
    int mn = min(min(min(min(f0.x, f0.y), min(f0.z, f0.w)),                \
                     min(min(f1.x, f1.y), min(f1.z, f1.w))),               \
                 min(min(min(f2.x, f2.y), min(f2.z, f2.w)),                \
                     min(min(f3.x, f3.y), min(f3.z, f3.w))));              \
    mn = min(mn, min(min(min(min(f4.x, f4.y), min(f4.z, f4.w)),            \
                         min(min(f5.x, f5.y), min(f5.z, f5.w))),           \
                     min(min(min(f6.x, f6.y), min(f6.z, f6.w)),            \
                         min(min(f7.x, f7.y), min(f7.z, f7.w)))));         \
    int mx = max(max(max(max(f0.x, f0.y), max(f0.z, f0.w)),                \
                     max(max(f1.x, f1.y), max(f1.z, f1.w))),               \
                 max(max(max(f2.x, f2.y), max(f2.z, f2.w)),                \
                     max(max(f3.x, f3.y), max(f3.z, f3.w))));              \
    mx = max(mx, max(max(max(max(f4.x, f4.y), max(f4.z, f4.w)),            \
                         max(max(f5.x, f5.y), max(f5.z, f5.w))),           \
                     max(max(max(f6.x, f6.y), max(f6.z, f6.w)),            \
                         max(max(f7.x, f7.y), max(f7.z, f7.w)))));         \
    return make_int2(mn, mx);

__device__ __forceinline__ int2 poll_row_sc1(const int* p) { POLL_ROW_BODY("", "sc1") }
__device__ __forceinline__ int2 poll_row_inv(const int* p) {
    POLL_ROW_BODY("buffer_inv\n\ts_waitcnt vmcnt(0)\n\t", "")
}

// Zero the sc1-read control regions only (slow flags, xcd, canary).
__global__ __launch_bounds__(256) void zero_kernel(char* ws)
{
    const int tid = threadIdx.x, wg = blockIdx.x;
    u32x4 z = {0, 0, 0, 0};
    if (wg == 0) {
        char* p = ws + SLOW_FLAG_OFF + tid * 16;   // 4 KiB
        asm volatile("global_store_dwordx4 %0, %1, off sc1" :: "v"(p), "v"(z) : "memory");
    } else if (tid < 192) {
        char* p = ws + XCD_OFF + tid * 16;         // 3 KiB: xcd + T + C
        asm volatile("global_store_dwordx4 %0, %1, off sc1" :: "v"(p), "v"(z) : "memory");
    }
}

// Persistent GRU kernel. WG (bg, hs): batch rows [bg*64,+64), units [hs*16,+16).
// Base = round 7 (best: 2818us). Stores: ALWAYS sc1 (proven write-through to
// the coherence point). Reads (h + fast flags): if the group is same-XCD AND
// the in-kernel canary proves "same-XCD sc1 store + buffer_inv + plain load
// sees the new value", use buffer_inv + plain loads (local-L2 service);
// otherwise sc1 reads (exact round-7 behavior). Producers store both flag
// sets so mixed verdicts interoperate. t=0 uses a[]=0 (h0 == 0), so no fast
// read ever touches a line not written by a same-XCD sc1 store this replay.
__global__ __launch_bounds__(NTHREADS, 1) void gru_kernel(
    const float* __restrict__ z_seq, const float* __restrict__ W_ih,
    const float* __restrict__ W_hh, const float* __restrict__ b_ih,
    const float* __restrict__ b_hh, const float* __restrict__ W_out,
    const float* __restrict__ b_out, float* __restrict__ out,
    char* __restrict__ ws, int allow_fast)
{
    __shared__ unsigned short s_w[LDS_SH];
    __shared__ int s_fast;
    const int tid = threadIdx.x;
    const int wg  = blockIdx.x;
    const int bg  = wg & 7;
    const int hs  = wg >> 3;

    unsigned short* hbuf = (unsigned short*)ws;
    int* sfl  = (int*)(ws + SLOW_FLAG_OFF) + bg * 64;   // 32 used, 256B stride
    int* ffl  = (int*)(ws + FAST_FLAG_OFF) + bg * 64;
    int* xrow = (int*)(ws + XCD_OFF)  + bg * 32;
    int* T    = (int*)(ws + CANT_OFF) + bg * 32;
    int* C    = (int*)(ws + CANC_OFF) + bg * 32;

    // ---- stage weights in fragment-linear order (fp32 -> bf16) ----
    for (int i = tid; i < 24576; i += NTHREADS) {
        int e = i & 7, ln = (i >> 3) & 63, ks = (i >> 9) & 15, g = i >> 13;
        int unit = hs * 16 + (ln & 15);
        int k = ks * 32 + (ln >> 4) * 8 + e;
        s_w[i] = f2bf(W_hh[(g * 512 + unit) * 512 + k]);
    }
    for (int i = tid; i < 6144; i += NTHREADS) {
        int e = i & 7, ln = (i >> 3) & 63, ks = (i >> 9) & 3, g = i >> 11;
        int unit = hs * 16 + (ln & 15);
        int k = ks * 32 + (ln >> 4) * 8 + e;
        s_w[OFF_WIH + i] = f2bf(W_ih[(g * 512 + unit) * 128 + k]);
    }
    for (int i = tid; i < 8192; i += NTHREADS) {
        int e = i & 7, ln = (i >> 3) & 63, ks = i >> 9;
        int ocol = hs * 4 + (ln & 3);           // cols duplicated x4
        int k = ks * 32 + (ln >> 4) * 8 + e;
        s_w[OFF_WOUT + i] = f2bf(W_out[ocol * 512 + k]);
    }

    // ---- startup: fast-flag self-init, XCD check, canary probe ----
    unsigned xcd;
    asm volatile("s_getreg_b32 %0, hwreg(20, 0, 32)" : "=s"(xcd));
    xcd &= 255u;
    if (tid == 0) {
        int z0 = 0;
        asm volatile("global_store_dword %0, %1, off sc1" :: "v"(ffl + hs), "v"(z0) : "memory");
        asm volatile("s_waitcnt vmcnt(0)" ::: "memory");   // init ordered before xcd publish
        int xv = (int)xcd + 1;
        asm volatile("global_store_dword %0, %1, off sc1" :: "v"(xrow + hs), "v"(xv) : "memory");

        if (hs == 0) {               // canary writer
            unsigned long long tm;
            asm volatile("s_memtime %0" : "=s"(tm));
            int m1 = (int)((unsigned)tm | 1u);
            asm volatile("global_store_dword %0, %1, off sc1" :: "v"(T), "v"(m1) : "memory");
            asm volatile("s_waitcnt vmcnt(0)" ::: "memory");
            asm volatile("global_store_dword %0, %1, off sc1" :: "v"(C), "v"(m1) : "memory");
            int p = 1000000;
            while (poll_word_sc1(C + 1) == 0 && --p) {}
            if (p) {
                int m2 = m1 ^ 0x5A5A5A5A;
                asm volatile("global_store_dword %0, %1, off sc1" :: "v"(T), "v"(m2) : "memory");
                asm volatile("s_waitcnt vmcnt(0)" ::: "memory");
                int one = 1;
                asm volatile("global_store_dword %0, %1, off sc1" :: "v"(C + 2), "v"(one) : "memory");
            }
        } else if (hs == 1) {        // canary reader (primes, then verifies)
            int p = 1000000, m1;
            while ((m1 = poll_word_sc1(C)) == 0 && --p) {}
            int verdict = 1;
            if (p) {
                int pv;  // PRIME: plain read caches the line in this XCD's L1/L2
                asm volatile("global_load_dword %0, %1, off\n\ts_waitcnt vmcnt(0)"
                             : "=v"(pv) : "v"(T) : "memory");
                asm volatile("" :: "v"(pv));
                int one = 1;
                asm volatile("global_store_dword %0, %1, off sc1" :: "v"(C + 1), "v"(one) : "memory");
                int q = 1000000;
                while (poll_word_sc1(C + 2) == 0 && --q) {}
                if (q) {
                    int v2;  // the actual hazard test: inv + plain read
                    asm volatile("buffer_inv\n\ts_waitcnt vmcnt(0)\n\t"
                                 "global_load_dword %0, %1, off\n\ts_waitcnt vmcnt(0)"
                                 : "=v"(v2) : "v"(T) : "memory");
                    verdict = (v2 == (m1 ^ 0x5A5A5A5A)) ? 2 : 1;
                }
            }
            asm volatile("global_store_dword %0, %1, off sc1" :: "v"(C + 3), "v"(verdict) : "memory");
        }

        int ok = 0, p2 = 1000000;
        for (;;) {
            int2 mm = poll_row_sc1(xrow);
            if (mm.x > 0) { ok = (mm.x == mm.y); break; }
            if (--p2 == 0) break;
        }
        int vd = 0, p3 = 1000000;
        while ((vd = poll_word_sc1(C + 3)) == 0 && --p3) {}
        s_fast = (allow_fast && ok && vd == 2) ? 1 : 0;
    }
    __syncthreads();
    const bool fast = (s_fast != 0);

    const int lane = tid & 63;
    const int wave = tid >> 6;
    const int li   = lane & 15;
    const int kq   = lane >> 4;
    const int jg   = hs * 16 + li;

    const float bihr = b_ih[jg], bihz = b_ih[NH + jg], bihn = b_ih[2 * NH + jg];
    const float bhhr = b_hh[jg], bhhz = b_hh[NH + jg], bhhn = b_hh[2 * NH + jg];
    const float bo   = b_out[hs * 4 + (li & 3)];

    const int aRow = bg * BT + wave * 16 + li;
    const int cRow = bg * BT + wave * 16 + kq * 4;
    float hreg[4] = {0.f, 0.f, 0.f, 0.f};

    const unsigned short* fb = s_w + lane * 8;
    unsigned short* tr = s_w + OFF_TR + wave * 384;
    int dead = 0;

    // ---- prologue: input-side pre-activations for t = 0 ----
    f32x4 ir = {0,0,0,0}, iz = {0,0,0,0}, in = {0,0,0,0};
    {
        const float* zrow = z_seq + ((long)aRow * SEQL + 0) * NIN + kq * 8;
#pragma unroll
        for (int ks = 0; ks < 4; ++ks) {
            float4 z0 = *(const float4*)(zrow + ks * 32);
            float4 z1 = *(const float4*)(zrow + ks * 32 + 4);
            union { bf16x8 v; unsigned short u[8]; } az;
            az.u[0] = f2bf(z0.x); az.u[1] = f2bf(z0.y);
            az.u[2] = f2bf(z0.z); az.u[3] = f2bf(z0.w);
            az.u[4] = f2bf(z1.x); az.u[5] = f2bf(z1.y);
            az.u[6] = f2bf(z1.z); az.u[7] = f2bf(z1.w);
            ir = MFMA(az.v, *(const bf16x8*)(fb + OFF_WIH + ks * 512), ir, 0, 0, 0);
            iz = MFMA(az.v, *(const bf16x8*)(fb + OFF_WIH + 2048 + ks * 512), iz, 0, 0, 0);
            in = MFMA(az.v, *(const bf16x8*)(fb + OFF_WIH + 4096 + ks * 512), in, 0, 0, 0);
        }
    }

    auto body = [&](auto FC) {
        constexpr bool FAST = decltype(FC)::value;
        for (int t = 0; t <= NSTEP; ++t) {
            const unsigned short* hin  = hbuf + (t & 1) * (BATCH * NH);
            unsigned short*       hout = hbuf + ((t & 1) ^ 1) * (BATCH * NH);

            // A fragments. t=0: h0 == 0, no load. FAST: plain loads — the
            // successful poll iteration just ran buffer_inv, and every store
            // to these lines is a same-XCD sc1 store (canary-verified fresh).
            bf16x8 a[16];
            if (t == 0) {
                bf16x8 az = {0,0,0,0,0,0,0,0};
#pragma unroll
                for (int ks = 0; ks < 16; ++ks) a[ks] = az;
            } else {
                const unsigned short* hrow = hin + aRow * NH + kq * 8;
#pragma unroll
                for (int ks = 0; ks < 16; ++ks) {
                    if constexpr (FAST)
                        asm volatile("global_load_dwordx4 %0, %1, off offset:%2"
                                     : "=v"(a[ks]) : "v"(hrow), "i"(ks * 64) : "memory");
                    else
                        asm volatile("global_load_dwordx4 %0, %1, off offset:%2 sc1"
                                     : "=v"(a[ks]) : "v"(hrow), "i"(ks * 64) : "memory");
                }
                asm volatile("s_waitcnt vmcnt(0)" ::: "memory");
                __builtin_amdgcn_sched_barrier(0);
            }

            // decode: a[] holds h_t; y_td needs h_{SEQL+1+td} -> t = SEQL+1+td
            if (t > SEQL) {
                int td = t - SEQL - 1;
                f32x4 y4 = {0, 0, 0, 0};
#pragma unroll
                for (int ks = 0; ks < 16; ++ks)
                    y4 = MFMA(a[ks], *(const bf16x8*)(fb + OFF_WOUT + ks * 512), y4, 0, 0, 0);
                if (li < 4) {
#pragma unroll
                    for (int q = 0; q < 4; ++q)
                        out[((long)(cRow + q) * PRED + td) * NOUT + hs * 4 + li] = y4[q] + bo;
                }
            }
            if (t == NSTEP) break;

            // hidden-side MFMA: fragment-linear B reads (conflict-free)
            f32x4 hr = {0,0,0,0}, hz = {0,0,0,0}, hn = {0,0,0,0};
#pragma unroll
            for (int ks = 0; ks < 16; ++ks) {
                hr = MFMA(a[ks], *(const bf16x8*)(fb + ks * 512), hr, 0, 0, 0);
                hz = MFMA(a[ks], *(const bf16x8*)(fb + 8192 + ks * 512), hz, 0, 0, 0);
                hn = MFMA(a[ks], *(const bf16x8*)(fb + 16384 + ks * 512), hn, 0, 0, 0);
            }

            // gate math -> bf16 into per-wave LDS transpose tile (stride 24)
#pragma unroll
            for (int q = 0; q < 4; ++q) {
                float r  = sigm(bihr + ir[q] + bhhr + hr[q]);
                float zz = sigm(bihz + iz[q] + bhhz + hz[q]);
                float nn = tanh_f(bihn + in[q] + r * (bhhn + hn[q]));
                float hq = (1.f - zz) * nn + zz * hreg[q];
                hreg[q]  = hq;
                tr[(kq * 4 + q) * 24 + li] = f2bf(hq);
            }
            asm volatile("s_waitcnt lgkmcnt(0)" ::: "memory");
            __builtin_amdgcn_sched_barrier(0);

            // coalesced h store: ALWAYS sc1 (proven write-through)
            if (lane < 32) {
                bf16x8 hv = *(const bf16x8*)(tr + (lane >> 1) * 24 + (lane & 1) * 8);
                int grow = bg * BT + wave * 16 + (lane >> 1);
                unsigned short* hp = hout + grow * NH + hs * 16 + (lane & 1) * 8;
                asm volatile("global_store_dwordx4 %0, %1, off sc1"
                             :: "v"(hp), "v"(hv) : "memory");
            }
            asm volatile("s_waitcnt vmcnt(0)" ::: "memory");
            __syncthreads();
            if (tid == 0) {     // dual flag store: slow + fast sets
                int v = t + 1;
                asm volatile("global_store_dword %0, %1, off sc1"
                             :: "v"(sfl + hs), "v"(v) : "memory");
                asm volatile("global_store_dword %0, %1, off sc1"
                             :: "v"(ffl + hs), "v"(v) : "memory");
            }

            // ---- barrier shadow: input-side pre-activations for t+1 ----
            f32x4 nir = {0,0,0,0}, niz = {0,0,0,0}, nin = {0,0,0,0};
            if (t + 1 < SEQL) {
                const float* zrow = z_seq + ((long)aRow * SEQL + (t + 1)) * NIN + kq * 8;
#pragma unroll
                for (int ks = 0; ks < 4; ++ks) {
                    float4 z0 = *(const float4*)(zrow + ks * 32);
                    float4 z1 = *(const float4*)(zrow + ks * 32 + 4);
                    union { bf16x8 v; unsigned short u[8]; } az;
                    az.u[0] = f2bf(z0.x); az.u[1] = f2bf(z0.y);
                    az.u[2] = f2bf(z0.z); az.u[3] = f2bf(z0.w);
                    az.u[4] = f2bf(z1.x); az.u[5] = f2bf(z1.y);
                    az.u[6] = f2bf(z1.z); az.u[7] = f2bf(z1.w);
                    nir = MFMA(az.v, *(const bf16x8*)(fb + OFF_WIH + ks * 512), nir, 0, 0, 0);
                    niz = MFMA(az.v, *(const bf16x8*)(fb + OFF_WIH + 2048 + ks * 512), niz, 0, 0, 0);
                    nin = MFMA(az.v, *(const bf16x8*)(fb + OFF_WIH + 4096 + ks * 512), nin, 0, 0, 0);
                }
            }

            // ---- flag poll: min over the group's 32 flags >= t+1 ----
            const int target = t + 1;
            int bail = 0;
            if (!dead && lane == 0) {
                int patience = 1000000;
                for (;;) {
                    int2 mm;
                    if constexpr (FAST) mm = poll_row_inv(ffl);
                    else                mm = poll_row_sc1(sfl);
                    if (mm.x >= target) break;
                    if (--patience == 0) { bail = 1; break; }
                }
            }
            dead |= __builtin_amdgcn_readfirstlane(bail);
            __builtin_amdgcn_sched_barrier(0);

            ir = nir; iz = niz; in = nin;
        }
    };
    if (fast) body(BC<true>{});
    else      body(BC<false>{});
}

extern "C" void kernel_launch(void* const* d_in, const int* in_sizes, int n_in,
                              void* d_out, int out_size, void* d_ws, size_t ws_size,
                              hipStream_t stream)
{
    const float* z_seq = (const float*)d_in[0];
    const float* W_ih  = (const float*)d_in[1];
    const float* W_hh  = (const float*)d_in[2];
    const float* b_ih  = (const float*)d_in[3];
    const float* b_hh  = (const float*)d_in[4];
    const float* W_out = (const float*)d_in[5];
    const float* b_out = (const float*)d_in[6];
    float* out = (float*)d_out;

    int allow_fast = (ws_size >= (size_t)WS_NEED) ? 1 : 0;

    zero_kernel<<<dim3(2), dim3(256), 0, stream>>>((char*)d_ws);
    gru_kernel<<<dim3(NWG), dim3(NTHREADS), 0, stream>>>(
        z_seq, W_ih, W_hh, b_ih, b_hh, W_out, b_out, out,
        (char*)d_ws, allow_fast);
}

// Round 15
// 2745.825 us; speedup vs baseline: 3.3202x; 1.0087x over previous
//
#include <hip/hip_runtime.h>

#define BATCH 512
#define SEQL  512
#define NIN   128
#define NH    512
#define NOUT  128
#define PRED  32
#define NSTEP (SEQL + PRED)

#define G_B 8
#define G_H 32
#define BT  64
#define NWG (G_B * G_H)
#define NTHREADS 256

// LDS layout (shorts), weights in MFMA-FRAGMENT order (proven: bank
// conflicts 1.33e8 -> 1.1e6): frag f base = f*512 + lane*8 -> each
// ds_read_b128 is perfectly linear per instruction (lane*16B).
#define OFF_WIH  24576
#define OFF_WOUT 30720
#define OFF_TR   38912
#define LDS_SH   40448

typedef short bf16x8 __attribute__((ext_vector_type(8)));
typedef float f32x4 __attribute__((ext_vector_type(4)));
typedef unsigned int u32x4 __attribute__((ext_vector_type(4)));

#define MFMA __builtin_amdgcn_mfma_f32_16x16x32_bf16

__device__ __forceinline__ unsigned short f2bf(float f) {
    unsigned int u = __float_as_uint(f);
    u = (u + 0x7fffu + ((u >> 16) & 1u)) >> 16;   // RTNE
    return (unsigned short)u;
}
__device__ __forceinline__ float sigm(float x) {
    x = fminf(fmaxf(x, -30.f), 30.f);
    return 1.f / (1.f + __expf(-x));
}
__device__ __forceinline__ float tanh_f(float x) {
    x = fminf(fmaxf(x, -15.f), 15.f);
    float e = __expf(2.f * x);
    return (e - 1.f) / (e + 1.f);
}

// Zero the flag rows (8 groups x 64 ints) with sc1 stores (land at the
// chip-coherent MALL point). hbuf needs no zeroing: t=0 uses a[]=0 (h0==0)
// and buffer 0 is first READ at t=2, after being written at t=1.
__global__ __launch_bounds__(256) void zero_kernel(int* cnt)
{
    const int tid = threadIdx.x;
    u32x4 z = {0, 0, 0, 0};
    if (tid < 128) {
        char* p = (char*)cnt + tid * 16;   // 2 KiB
        asm volatile("global_store_dwordx4 %0, %1, off sc1" :: "v"(p), "v"(z) : "memory");
    }
}

// Persistent GRU kernel. WG (bg, hs): batch rows [bg*64,+64), units [hs*16,+16).
// CONVERGED STRUCTURE (rounds 1-14): sc1 stores/loads for all h/flag exchange
// (the chip-coherent MALL point is the only correct path — plain/sc0/
// buffer_inv local-L2 variants all measured stale), G_H=32 (measured optimum
// of the broadcast-traffic vs wave-count trade), per-WG flag word stored
// after vmcnt(0) drain + __syncthreads, per-wave lane-0 flag-vector poll
// (plain sc1 dwordx4, no RMW — RMW polls serialize at the MALL atomic unit),
// fragment-linear LDS weights (conflict-free ds_read_b128), LDS-transposed
// coalesced h stores, input-side z MFMA hoisted into the barrier-wait shadow,
// fused decode y = h @ Wout^T as MFMA on the already-loaded A fragments.
__global__ __launch_bounds__(NTHREADS, 1) void gru_kernel(
    const float* __restrict__ z_seq, const float* __restrict__ W_ih,
    const float* __restrict__ W_hh, const float* __restrict__ b_ih,
    const float* __restrict__ b_hh, const float* __restrict__ W_out,
    const float* __restrict__ b_out, float* __restrict__ out,
    unsigned short* __restrict__ hbuf, int* __restrict__ cnt)
{
    __shared__ unsigned short s_w[LDS_SH];
    const int tid = threadIdx.x;
    const int wg  = blockIdx.x;
    const int bg  = wg & 7;
    const int hs  = wg >> 3;

    // ---- stage weights in fragment-linear order (fp32 -> bf16) ----
    for (int i = tid; i < 24576; i += NTHREADS) {
        int e = i & 7, ln = (i >> 3) & 63, ks = (i >> 9) & 15, g = i >> 13;
        int unit = hs * 16 + (ln & 15);
        int k = ks * 32 + (ln >> 4) * 8 + e;
        s_w[i] = f2bf(W_hh[(g * 512 + unit) * 512 + k]);
    }
    for (int i = tid; i < 6144; i += NTHREADS) {
        int e = i & 7, ln = (i >> 3) & 63, ks = (i >> 9) & 3, g = i >> 11;
        int unit = hs * 16 + (ln & 15);
        int k = ks * 32 + (ln >> 4) * 8 + e;
        s_w[OFF_WIH + i] = f2bf(W_ih[(g * 512 + unit) * 128 + k]);
    }
    for (int i = tid; i < 8192; i += NTHREADS) {
        int e = i & 7, ln = (i >> 3) & 63, ks = i >> 9;
        int ocol = hs * 4 + (ln & 3);           // cols duplicated x4
        int k = ks * 32 + (ln >> 4) * 8 + e;
        s_w[OFF_WOUT + i] = f2bf(W_out[ocol * 512 + k]);
    }
    __syncthreads();

    const int lane = tid & 63;
    const int wave = tid >> 6;
    const int li   = lane & 15;       // MFMA row-of-A / col-of-B / col-of-C
    const int kq   = lane >> 4;       // k-chunk selector
    const int jg   = hs * 16 + li;    // global hidden unit of this lane

    const float bihr = b_ih[jg], bihz = b_ih[NH + jg], bihn = b_ih[2 * NH + jg];
    const float bhhr = b_hh[jg], bhhz = b_hh[NH + jg], bhhn = b_hh[2 * NH + jg];
    const float bo   = b_out[hs * 4 + (li & 3)];

    const int aRow = bg * BT + wave * 16 + li;        // batch row for A frags
    const int cRow = bg * BT + wave * 16 + kq * 4;    // C rows (+q)
    float hreg[4] = {0.f, 0.f, 0.f, 0.f};             // fp32 h state in regs

    const unsigned short* fb = s_w + lane * 8;            // per-lane frag base
    unsigned short* tr = s_w + OFF_TR + wave * 384;       // transpose scratch

    int* gflags = cnt + bg * 64;          // 32 flag ints per group, 256B apart
    int* myFlag = gflags + hs;
    int  dead   = 0;

    // ---- prologue: input-side pre-activations for t = 0 ----
    f32x4 ir = {0,0,0,0}, iz = {0,0,0,0}, in = {0,0,0,0};
    {
        const float* zrow = z_seq + ((long)aRow * SEQL + 0) * NIN + kq * 8;
#pragma unroll
        for (int ks = 0; ks < 4; ++ks) {
            float4 z0 = *(const float4*)(zrow + ks * 32);
            float4 z1 = *(const float4*)(zrow + ks * 32 + 4);
            union { bf16x8 v; unsigned short u[8]; } az;
            az.u[0] = f2bf(z0.x); az.u[1] = f2bf(z0.y);
            az.u[2] = f2bf(z0.z); az.u[3] = f2bf(z0.w);
            az.u[4] = f2bf(z1.x); az.u[5] = f2bf(z1.y);
            az.u[6] = f2bf(z1.z); az.u[7] = f2bf(z1.w);
            ir = MFMA(az.v, *(const bf16x8*)(fb + OFF_WIH + ks * 512), ir, 0, 0, 0);
            iz = MFMA(az.v, *(const bf16x8*)(fb + OFF_WIH + 2048 + ks * 512), iz, 0, 0, 0);
            in = MFMA(az.v, *(const bf16x8*)(fb + OFF_WIH + 4096 + ks * 512), in, 0, 0, 0);
        }
    }

    for (int t = 0; t <= NSTEP; ++t) {
        const unsigned short* hin  = hbuf + (t & 1) * (BATCH * NH);
        unsigned short*       hout = hbuf + ((t & 1) ^ 1) * (BATCH * NH);

        // A fragments. t=0: h0 == 0, no load (skips one MALL round trip and
        // makes hbuf-zeroing unnecessary). Else: sc1 agent-scope loads from
        // the MALL coherence point.
        bf16x8 a[16];
        if (t == 0) {
            bf16x8 az = {0,0,0,0,0,0,0,0};
#pragma unroll
            for (int ks = 0; ks < 16; ++ks) a[ks] = az;
        } else {
            const unsigned short* hrow = hin + aRow * NH + kq * 8;
#pragma unroll
            for (int ks = 0; ks < 16; ++ks)
                asm volatile("global_load_dwordx4 %0, %1, off offset:%2 sc1"
                             : "=v"(a[ks]) : "v"(hrow), "i"(ks * 64) : "memory");
            asm volatile("s_waitcnt vmcnt(0)" ::: "memory");
            __builtin_amdgcn_sched_barrier(0);
        }

        // decode: a[] holds h_t; y_td needs h_{SEQL+1+td} -> emit at t=SEQL+1+td
        if (t > SEQL) {
            int td = t - SEQL - 1;
            f32x4 y4 = {0, 0, 0, 0};
#pragma unroll
            for (int ks = 0; ks < 16; ++ks)
                y4 = MFMA(a[ks], *(const bf16x8*)(fb + OFF_WOUT + ks * 512), y4, 0, 0, 0);
            if (li < 4) {
#pragma unroll
                for (int q = 0; q < 4; ++q)
                    out[((long)(cRow + q) * PRED + td) * NOUT + hs * 4 + li] = y4[q] + bo;
            }
        }
        if (t == NSTEP) break;

        // hidden-side MFMA: fragment-linear B reads (zero bank conflicts)
        f32x4 hr = {0,0,0,0}, hz = {0,0,0,0}, hn = {0,0,0,0};
#pragma unroll
        for (int ks = 0; ks < 16; ++ks) {
            hr = MFMA(a[ks], *(const bf16x8*)(fb + ks * 512), hr, 0, 0, 0);
            hz = MFMA(a[ks], *(const bf16x8*)(fb + 8192 + ks * 512), hz, 0, 0, 0);
            hn = MFMA(a[ks], *(const bf16x8*)(fb + 16384 + ks * 512), hn, 0, 0, 0);
        }

        // gate math -> bf16 into per-wave LDS transpose tile (rows stride 24)
#pragma unroll
        for (int q = 0; q < 4; ++q) {
            float r  = sigm(bihr + ir[q] + bhhr + hr[q]);
            float zz = sigm(bihz + iz[q] + bhhz + hz[q]);
            float nn = tanh_f(bihn + in[q] + r * (bhhn + hn[q]));
            float hq = (1.f - zz) * nn + zz * hreg[q];
            hreg[q]  = hq;
            tr[(kq * 4 + q) * 24 + li] = f2bf(hq);
        }
        asm volatile("s_waitcnt lgkmcnt(0)" ::: "memory");
        __builtin_amdgcn_sched_barrier(0);

        // coalesced h store: 32 lanes x dwordx4 sc1 (16 rows x 2 chunks)
        if (lane < 32) {
            bf16x8 hv = *(const bf16x8*)(tr + (lane >> 1) * 24 + (lane & 1) * 8);
            int grow = bg * BT + wave * 16 + (lane >> 1);
            unsigned short* hp = hout + grow * NH + hs * 16 + (lane & 1) * 8;
            asm volatile("global_store_dwordx4 %0, %1, off sc1"
                         :: "v"(hp), "v"(hv) : "memory");
        }
        asm volatile("s_waitcnt vmcnt(0)" ::: "memory");
        __syncthreads();
        if (tid == 0) {
            int v = t + 1;
            asm volatile("global_store_dword %0, %1, off sc1"
                         :: "v"(myFlag), "v"(v) : "memory");
        }

        // ---- barrier shadow: input-side pre-activations for t+1 ----
        f32x4 nir = {0,0,0,0}, niz = {0,0,0,0}, nin = {0,0,0,0};
        if (t + 1 < SEQL) {
            const float* zrow = z_seq + ((long)aRow * SEQL + (t + 1)) * NIN + kq * 8;
#pragma unroll
            for (int ks = 0; ks < 4; ++ks) {
                float4 z0 = *(const float4*)(zrow + ks * 32);
                float4 z1 = *(const float4*)(zrow + ks * 32 + 4);
                union { bf16x8 v; unsigned short u[8]; } az;
                az.u[0] = f2bf(z0.x); az.u[1] = f2bf(z0.y);
                az.u[2] = f2bf(z0.z); az.u[3] = f2bf(z0.w);
                az.u[4] = f2bf(z1.x); az.u[5] = f2bf(z1.y);
                az.u[6] = f2bf(z1.z); az.u[7] = f2bf(z1.w);
                nir = MFMA(az.v, *(const bf16x8*)(fb + OFF_WIH + ks * 512), nir, 0, 0, 0);
                niz = MFMA(az.v, *(const bf16x8*)(fb + OFF_WIH + 2048 + ks * 512), niz, 0, 0, 0);
                nin = MFMA(az.v, *(const bf16x8*)(fb + OFF_WIH + 4096 + ks * 512), nin, 0, 0, 0);
            }
        }

        // ---- flag-vector poll: plain sc1 loads of the 32 group flags ----
        // "=&v" early-clobber mandatory (round-6 crash lesson).
        const int target = t + 1;
        int bail = 0;
        if (!dead && lane == 0) {
            int patience = 2000000;
            for (;;) {
                int4 f0, f1, f2, f3, f4, f5, f6, f7;
                asm volatile(
                    "global_load_dwordx4 %0, %8, off sc1\n\t"
                    "global_load_dwordx4 %1, %8, off offset:16 sc1\n\t"
                    "global_load_dwordx4 %2, %8, off offset:32 sc1\n\t"
                    "global_load_dwordx4 %3, %8, off offset:48 sc1\n\t"
                    "global_load_dwordx4 %4, %8, off offset:64 sc1\n\t"
                    "global_load_dwordx4 %5, %8, off offset:80 sc1\n\t"
                    "global_load_dwordx4 %6, %8, off offset:96 sc1\n\t"
                    "global_load_dwordx4 %7, %8, off offset:112 sc1\n\t"
                    "s_waitcnt vmcnt(0)"
                    : "=&v"(f0), "=&v"(f1), "=&v"(f2), "=&v"(f3),
                      "=&v"(f4), "=&v"(f5), "=&v"(f6), "=&v"(f7)
                    : "v"(gflags) : "memory");
                int m0 = min(min(min(f0.x, f0.y), min(f0.z, f0.w)),
                             min(min(f1.x, f1.y), min(f1.z, f1.w)));
                int m1 = min(min(min(f2.x, f2.y), min(f2.z, f2.w)),
                             min(min(f3.x, f3.y), min(f3.z, f3.w)));
                int m2 = min(min(min(f4.x, f4.y), min(f4.z, f4.w)),
                             min(min(f5.x, f5.y), min(f5.z, f5.w)));
                int m3 = min(min(min(f6.x, f6.y), min(f6.z, f6.w)),
                             min(min(f7.x, f7.y), min(f7.z, f7.w)));
                if (min(min(m0, m1), min(m2, m3)) >= target) break;
                if (--patience == 0) { bail = 1; break; }
            }
        }
        dead |= __builtin_amdgcn_readfirstlane(bail);
        __builtin_amdgcn_sched_barrier(0);

        ir = nir; iz = niz; in = nin;
    }
}

extern "C" void kernel_launch(void* const* d_in, const int* in_sizes, int n_in,
                              void* d_out, int out_size, void* d_ws, size_t ws_size,
                              hipStream_t stream)
{
    const float* z_seq = (const float*)d_in[0];
    const float* W_ih  = (const float*)d_in[1];
    const float* W_hh  = (const float*)d_in[2];
    const float* b_ih  = (const float*)d_in[3];
    const float* b_hh  = (const float*)d_in[4];
    const float* W_out = (const float*)d_in[5];
    const float* b_out = (const float*)d_in[6];
    float* out = (float*)d_out;

    unsigned short* hbuf = (unsigned short*)d_ws;                   // 2 x [512][512] bf16
    int* cnt = (int*)((char*)d_ws + (size_t)2 * BATCH * NH * 2);    // 8 x 64 flag ints

    zero_kernel<<<dim3(1), dim3(256), 0, stream>>>(cnt);
    gru_kernel<<<dim3(NWG), dim3(NTHREADS), 0, stream>>>(
        z_seq, W_ih, W_hh, b_ih, b_hh, W_out, b_out, out, hbuf, cnt);
}